// Round 1
// 682.884 us; speedup vs baseline: 1.0547x; 1.0547x over previous
//
#include <hip/hip_runtime.h>
#include <hip/hip_bf16.h>

// ReprogrammingLayer: q=QWq+bq; k=KsWk+bk; v=VsWv+bv (8 heads, E=128);
// A=softmax(qk^T/sqrt(512)); out=(Av)Wo+bo.
// I/O FP32 (reference dtypes); internal bf16 MFMA + fp32 accum (2% threshold).
// scale*log2(e) is folded into Wq/bq so attention softmax runs in base-2.
//
// ws layout (bf16 elems, peak 33M = 66MB):
//   qb[8M]@0 | kb[2M]@8M | vtb[2M]@10M | at[8M]@12M
//   WqT[1M]@20M | WkT[4M]@21M | WvT[4M]@25M | WoT[4M]@29M

typedef __bf16 bf16x8 __attribute__((ext_vector_type(8)));
typedef float  f32x4  __attribute__((ext_vector_type(4)));

union V16 { uint4 u; bf16x8 v; };
__device__ __forceinline__ bf16x8 ld16v(const void* p) {
  V16 t; t.u = *(const uint4*)p; return t.v;
}
__device__ __forceinline__ uint4 pack8(float4 a, float4 b) {
  V16 t;
  t.v[0] = (__bf16)a.x; t.v[1] = (__bf16)a.y; t.v[2] = (__bf16)a.z; t.v[3] = (__bf16)a.w;
  t.v[4] = (__bf16)b.x; t.v[5] = (__bf16)b.y; t.v[6] = (__bf16)b.z; t.v[7] = (__bf16)b.w;
  return t.u;
}
// async global->LDS DMA, 16B/lane; LDS dest = wave-uniform base + lane*16
__device__ __forceinline__ void dma16(const void* g, void* l) {
  __builtin_amdgcn_global_load_lds(
      (const __attribute__((address_space(1))) unsigned int*)g,
      (__attribute__((address_space(3))) unsigned int*)l, 16, 0, 0);
}
// XOR-swizzled 16B-chunk index for a 128x32 bf16 tile (4 chunks/row).
__device__ __forceinline__ int chunk_of(int row, int gc) {
  return row * 4 + (gc ^ ((row >> 1) & 3));
}

// -------- weight transpose+convert+scale: W[K][N] fp32 -> Wt[N][K] bf16 ----
__global__ __launch_bounds__(256) void transpose_k(const float* __restrict__ W,
                                                   __bf16* __restrict__ Wt, int K, int N,
                                                   float scale) {
  __shared__ __bf16 t[32][33];
  int tx = threadIdx.x & 31, ty = threadIdx.x >> 5;
  int n0 = blockIdx.x * 32, k0 = blockIdx.y * 32;
#pragma unroll
  for (int r = 0; r < 32; r += 8)
    t[ty + r][tx] = (__bf16)(W[(size_t)(k0 + ty + r) * N + n0 + tx] * scale);
  __syncthreads();
#pragma unroll
  for (int r = 0; r < 32; r += 8) Wt[(size_t)(n0 + ty + r) * K + k0 + tx] = t[tx][ty + r];
}

// -------- GEMM core: C = A[M,K] @ Bt[N,K]^T + bscale*bias --------
// 128x128 tile, BK=32, 4 waves 2x2, 4x4 16x16x32 bf16 mfma frags.
template <typename AT, typename CT>
__device__ __forceinline__ void gemm_core(__bf16* As, __bf16* Bs,
                                          const AT* __restrict__ A,
                                          const __bf16* __restrict__ Bt,
                                          const float* __restrict__ bias,
                                          CT* __restrict__ C,
                                          int M, int N, int K, int lda, int trans,
                                          int m0, int n0, float bscale) {
  const int tid = threadIdx.x;
  const int lane = tid & 63, wave = tid >> 6;
  const int g = lane >> 4, l16 = lane & 15;
  const int wr = wave >> 1, wc = wave & 1;
  int aoff[4], boff[4];
#pragma unroll
  for (int mf = 0; mf < 4; mf++) aoff[mf] = chunk_of(wr * 64 + mf * 16 + l16, g) * 8;
#pragma unroll
  for (int nf = 0; nf < 4; nf++) boff[nf] = chunk_of(wc * 64 + nf * 16 + l16, g) * 8;

  f32x4 acc[4][4] = {};
  for (int k0 = 0; k0 < K; k0 += 32) {
    __syncthreads();
    if constexpr (sizeof(AT) == 2) {       // bf16 A: DMA, 2 issues/wave
#pragma unroll
      for (int rnd = 0; rnd < 2; rnd++) {
        int cstart = wave * 128 + rnd * 64;
        int p = cstart + lane;
        int row = p >> 2, gc = (p & 3) ^ ((row >> 1) & 3);
        dma16((const __bf16*)A + (size_t)(m0 + row) * lda + k0 + gc * 8,
              As + (size_t)cstart * 8);
      }
    } else {                               // fp32 A: load+convert
#pragma unroll
      for (int i = 0; i < 2; i++) {
        int p = tid + i * 256;
        int row = p >> 2, gc = (p & 3) ^ ((row >> 1) & 3);
        const float* ap = (const float*)A + (size_t)(m0 + row) * lda + k0 + gc * 8;
        float4 f0 = *(const float4*)ap;
        float4 f1 = *(const float4*)(ap + 4);
        *(uint4*)(As + p * 8) = pack8(f0, f1);
      }
    }
#pragma unroll
    for (int rnd = 0; rnd < 2; rnd++) {    // B: always bf16 DMA
      int cstart = wave * 128 + rnd * 64;
      int p = cstart + lane;
      int row = p >> 2, gc = (p & 3) ^ ((row >> 1) & 3);
      dma16(Bt + (size_t)(n0 + row) * (size_t)K + k0 + gc * 8,
            Bs + (size_t)cstart * 8);
    }
    __syncthreads();
    bf16x8 af[4], bff[4];
#pragma unroll
    for (int mf = 0; mf < 4; mf++) af[mf]  = ld16v(As + aoff[mf]);
#pragma unroll
    for (int nf = 0; nf < 4; nf++) bff[nf] = ld16v(Bs + boff[nf]);
#pragma unroll
    for (int mf = 0; mf < 4; mf++)
#pragma unroll
      for (int nf = 0; nf < 4; nf++)
        acc[mf][nf] = __builtin_amdgcn_mfma_f32_16x16x32_bf16(af[mf], bff[nf], acc[mf][nf], 0, 0, 0);
  }
#pragma unroll
  for (int nf = 0; nf < 4; nf++) {
    int col = n0 + wc * 64 + nf * 16 + l16;
    float bv = bias[col] * bscale;
#pragma unroll
    for (int mf = 0; mf < 4; mf++) {
      int rowb = m0 + wr * 64 + mf * 16 + g * 4;
      if constexpr (sizeof(CT) == 2) {
        if (trans) {
          union { __bf16 h[4]; uint2 u; } pk;
#pragma unroll
          for (int r = 0; r < 4; r++) pk.h[r] = (__bf16)(acc[mf][nf][r] + bv);
          *(uint2*)&((__bf16*)C)[(size_t)col * M + rowb] = pk.u;   // C^T[n][m]
        } else {
#pragma unroll
          for (int r = 0; r < 4; r++)
            ((__bf16*)C)[(size_t)(rowb + r) * N + col] = (__bf16)(acc[mf][nf][r] + bv);
        }
      } else {
#pragma unroll
        for (int r = 0; r < 4; r++)
          ((float*)C)[(size_t)(rowb + r) * N + col] = acc[mf][nf][r] + bv;
      }
    }
  }
}

__global__ __launch_bounds__(256) void gemm_f_b(const float* __restrict__ A,
                                                const __bf16* __restrict__ Bt,
                                                const float* __restrict__ bias,
                                                __bf16* __restrict__ C,
                                                int M, int N, int K, int lda, int trans,
                                                float bscale) {
  __shared__ __align__(16) __bf16 As[128 * 32];
  __shared__ __align__(16) __bf16 Bs[128 * 32];
  gemm_core<float, __bf16>(As, Bs, A, Bt, bias, C, M, N, K, lda, trans,
                           blockIdx.x * 128, blockIdx.y * 128, bscale);
}

__global__ __launch_bounds__(256) void gemm_b_f(const __bf16* __restrict__ A,
                                                const __bf16* __restrict__ Bt,
                                                const float* __restrict__ bias,
                                                float* __restrict__ C,
                                                int M, int N, int K, int lda, int trans) {
  __shared__ __align__(16) __bf16 As[128 * 32];
  __shared__ __align__(16) __bf16 Bs[128 * 32];
  gemm_core<__bf16, float>(As, Bs, A, Bt, bias, C, M, N, K, lda, trans,
                           blockIdx.x * 128, blockIdx.y * 128, 1.0f);
}

__global__ __launch_bounds__(256) void gemm_kv(const float* __restrict__ A0, const __bf16* __restrict__ B0t,
                                               const float* __restrict__ b0, __bf16* __restrict__ C0,
                                               const float* __restrict__ A1, const __bf16* __restrict__ B1t,
                                               const float* __restrict__ b1, __bf16* __restrict__ C1) {
  __shared__ __align__(16) __bf16 As[128 * 32];
  __shared__ __align__(16) __bf16 Bs[128 * 32];
  if (blockIdx.z == 0)
    gemm_core<float, __bf16>(As, Bs, A0, B0t, b0, C0, 2048, 1024, 4096, 4096, 0,
                             blockIdx.x * 128, blockIdx.y * 128, 1.0f);
  else
    gemm_core<float, __bf16>(As, Bs, A1, B1t, b1, C1, 2048, 1024, 4096, 4096, 1,
                             blockIdx.x * 128, blockIdx.y * 128, 1.0f);
}

// -------- flash attention --------
// Round-4 restructure (was: 128 q-rows/block, 512 blocks, VGPR 176, reg-staged
// K/V -> occupancy 11.5%, MfmaUtil 13%):
//  * QBLK=64, 4 waves x 16 q-rows, grid 128x8 = 1024 blocks (4 blocks/CU).
//  * K/V staged by global_load_lds (linear LDS dest, XOR-pre-swizzled global
//    source; reads apply same XOR) -> no staging VGPRs / LDS-write instrs.
//  * P tile [64][72] (affine, padded) aliases ks; barrier(3) protects alias.
//  * softmax in base-2; scale*log2e folded into Wq/bq upstream.
//  * LDS 33.8KB -> 4 blocks/CU; launch_bounds(256,4) targets VGPR<=128
//    -> 16 waves/CU (4x the old resident-wave count).
__global__ __launch_bounds__(256, 4) void attn_k(const __bf16* __restrict__ q,
                                                 const __bf16* __restrict__ k,
                                                 const __bf16* __restrict__ vt,
                                                 __bf16* __restrict__ o) {
  __shared__ __align__(16) union {
    __bf16 ks[64 * 128];   // K tile, 1024 swizzled 16B chunks (16 per row)
    __bf16 ps[64 * 72];    // P tile [q][s], +8 pad; written after ks dead
  } u;
  __shared__ __align__(16) __bf16 vs[128 * 64];  // V^T tile, 8 chunks/row
  const int tid = threadIdx.x, lane = tid & 63, wave = tid >> 6;
  const int g = lane >> 4, l16 = lane & 15;
  const int h = blockIdx.y, q0 = blockIdx.x * 64;

  bf16x8 qf[4];                    // Q rows q0+wave*16+l16 (scale pre-folded)
#pragma unroll
  for (int kk = 0; kk < 4; kk++)
    qf[kk] = ld16v(q + (size_t)(q0 + wave * 16 + l16) * 1024 + h * 128 + kk * 32 + g * 8);

  f32x4 accO[8] = {};
  float m_i[4], l_i[4];
#pragma unroll
  for (int r = 0; r < 4; r++) { m_i[r] = -1e30f; l_i[r] = 0.f; }

  for (int s0 = 0; s0 < 2048; s0 += 64) {
    __syncthreads();               // (1) all prior ks/ps/vs reads drained
#pragma unroll
    for (int i = 0; i < 4; i++) {  // K tile: 16KB, 16 wave-issues total
      int c = wave * 256 + i * 64 + lane;
      int row = c >> 4, gc = (c & 15) ^ (row & 7);
      dma16(k + (size_t)(s0 + row) * 1024 + h * 128 + gc * 8,
            u.ks + (wave * 256 + i * 64) * 8);
    }
#pragma unroll
    for (int i = 0; i < 4; i++) {  // V^T tile: 16KB
      int c = wave * 256 + i * 64 + lane;
      int row = c >> 3, cc = (c & 7) ^ (row & 7);
      dma16(vt + (size_t)(h * 128 + row) * 2048 + s0 + cc * 8,
            vs + (wave * 256 + i * 64) * 8);
    }
    __syncthreads();               // (2) vmcnt(0) drained by compiler

    f32x4 sc[4] = {};
    __builtin_amdgcn_s_setprio(1);
#pragma unroll
    for (int kk = 0; kk < 4; kk++) {  // QK^T, contract e=128
      bf16x8 kf[4];
#pragma unroll
      for (int nf = 0; nf < 4; nf++) {
        int row = nf * 16 + l16;
        kf[nf] = ld16v(u.ks + (row * 16 + ((kk * 4 + g) ^ (row & 7))) * 8);
      }
#pragma unroll
      for (int nf = 0; nf < 4; nf++)
        sc[nf] = __builtin_amdgcn_mfma_f32_16x16x32_bf16(qf[kk], kf[nf], sc[nf], 0, 0, 0);
    }
    __builtin_amdgcn_s_setprio(0);

    // online softmax, base-2 domain; row g*4+r lives in the 16 lanes of group g
#pragma unroll
    for (int r = 0; r < 4; r++) {
      float mx = fmaxf(fmaxf(sc[0][r], sc[1][r]), fmaxf(sc[2][r], sc[3][r]));
#pragma unroll
      for (int off = 1; off < 16; off <<= 1) mx = fmaxf(mx, __shfl_xor(mx, off));
      float mn = fmaxf(m_i[r], mx);
      float alpha = exp2f(m_i[r] - mn);
      float rs = 0.f;
#pragma unroll
      for (int nf = 0; nf < 4; nf++) {
        float p = exp2f(sc[nf][r] - mn);
        sc[nf][r] = p;
        rs += p;
      }
#pragma unroll
      for (int off = 1; off < 16; off <<= 1) rs += __shfl_xor(rs, off);
      m_i[r] = mn;
      l_i[r] = l_i[r] * alpha + rs;
#pragma unroll
      for (int ef = 0; ef < 8; ef++) accO[ef][r] *= alpha;
    }

    __syncthreads();               // (3) all waves' ks reads done; ps safe

#pragma unroll
    for (int nf = 0; nf < 4; nf++)
#pragma unroll
      for (int r = 0; r < 4; r++) {
        int prow = wave * 16 + g * 4 + r;
        u.ps[prow * 72 + nf * 16 + l16] = (__bf16)sc[nf][r];  // affine: 1 base + imm
      }

    // PV: wave reads only its own 16 ps rows (same-wave lgkm order suffices)
    __builtin_amdgcn_s_setprio(1);
#pragma unroll
    for (int kk = 0; kk < 2; kk++) {
      bf16x8 pf = ld16v(u.ps + (wave * 16 + l16) * 72 + kk * 32 + g * 8);
#pragma unroll
      for (int ef = 0; ef < 8; ef++) {
        int vrow = ef * 16 + l16;
        bf16x8 vf = ld16v(vs + (vrow * 8 + ((kk * 4 + g) ^ (vrow & 7))) * 8);
        accO[ef] = __builtin_amdgcn_mfma_f32_16x16x32_bf16(pf, vf, accO[ef], 0, 0, 0);
      }
    }
    __builtin_amdgcn_s_setprio(0);
  }

  float inv[4];
#pragma unroll
  for (int r = 0; r < 4; r++) inv[r] = 1.0f / l_i[r];
#pragma unroll
  for (int ef = 0; ef < 8; ef++)
#pragma unroll
    for (int r = 0; r < 4; r++) {
      int row = q0 + wave * 16 + g * 4 + r;
      o[(size_t)row * 1024 + h * 128 + ef * 16 + l16] = (__bf16)(accO[ef][r] * inv[r]);
    }
}

extern "C" void kernel_launch(void* const* d_in, const int* in_sizes, int n_in,
                              void* d_out, int out_size, void* d_ws, size_t ws_size,
                              hipStream_t stream) {
  const float* Q   = (const float*)d_in[0];
  const float* Ksr = (const float*)d_in[1];
  const float* Vsr = (const float*)d_in[2];
  const float* Wq  = (const float*)d_in[3];
  const float* bq  = (const float*)d_in[4];
  const float* Wk  = (const float*)d_in[5];
  const float* bk  = (const float*)d_in[6];
  const float* Wv  = (const float*)d_in[7];
  const float* bv  = (const float*)d_in[8];
  const float* Wo  = (const float*)d_in[9];
  const float* bo  = (const float*)d_in[10];
  __bf16* ws = (__bf16*)d_ws;
  const size_t MB = 1024 * 1024;
  __bf16* qb  = ws;             // [8192,1024] (pre-scaled by qscale)
  __bf16* kb  = ws + 8  * MB;   // [2048,1024]
  __bf16* vtb = ws + 10 * MB;   // [1024,2048] = v^T
  __bf16* at  = ws + 12 * MB;   // [8192,1024]
  __bf16* WqT = ws + 20 * MB;   // [1024,1024]
  __bf16* WkT = ws + 21 * MB;   // [1024,4096]
  __bf16* WvT = ws + 25 * MB;   // [1024,4096]
  __bf16* WoT = ws + 29 * MB;   // [4096,1024]

  // 1/sqrt(512) * log2(e): softmax computed as 2^x in attn_k
  const float qscale = 0.044194173824159216f * 1.4426950408889634f;

  transpose_k<<<dim3(32, 32),  256, 0, stream>>>(Wq, WqT, 1024, 1024, qscale);
  transpose_k<<<dim3(32, 128), 256, 0, stream>>>(Wk, WkT, 4096, 1024, 1.0f);
  transpose_k<<<dim3(32, 128), 256, 0, stream>>>(Wv, WvT, 4096, 1024, 1.0f);
  transpose_k<<<dim3(128, 32), 256, 0, stream>>>(Wo, WoT, 1024, 4096, 1.0f);

  gemm_f_b<<<dim3(64, 8), 256, 0, stream>>>(Q, WqT, bq, qb, 8192, 1024, 1024, 1024, 0, qscale);
  gemm_kv<<<dim3(16, 8, 2), 256, 0, stream>>>(Ksr, WkT, bk, kb, Vsr, WvT, bv, vtb);
  attn_k<<<dim3(128, 8), 256, 0, stream>>>(qb, kb, vtb, at);
  gemm_b_f<<<dim3(64, 32), 256, 0, stream>>>(at, WoT, bo, (float*)d_out, 8192, 4096, 1024, 1024, 0);
}

// Round 2
// 658.735 us; speedup vs baseline: 1.0934x; 1.0367x over previous
//
#include <hip/hip_runtime.h>
#include <hip/hip_bf16.h>

// ReprogrammingLayer: q=QWq+bq; k=KsWk+bk; v=VsWv+bv (8 heads, E=128);
// A=softmax(qk^T/sqrt(512)); out=(Av)Wo+bo.
// I/O FP32 (reference dtypes); internal bf16 MFMA + fp32 accum (2% threshold).
// scale*log2(e) is folded into Wq/bq so attention softmax runs in base-2.
//
// ws layout (bf16 elems, peak 33M = 66MB):
//   qb[8M]@0 | kb[2M]@8M | vtb[2M]@10M | at[8M]@12M
//   WqT[1M]@20M | WkT[4M]@21M | WvT[4M]@25M | WoT[4M]@29M

typedef __bf16 bf16x8 __attribute__((ext_vector_type(8)));
typedef float  f32x4  __attribute__((ext_vector_type(4)));

union V16 { uint4 u; bf16x8 v; };
__device__ __forceinline__ bf16x8 ld16v(const void* p) {
  V16 t; t.u = *(const uint4*)p; return t.v;
}
__device__ __forceinline__ uint4 pack8(float4 a, float4 b) {
  V16 t;
  t.v[0] = (__bf16)a.x; t.v[1] = (__bf16)a.y; t.v[2] = (__bf16)a.z; t.v[3] = (__bf16)a.w;
  t.v[4] = (__bf16)b.x; t.v[5] = (__bf16)b.y; t.v[6] = (__bf16)b.z; t.v[7] = (__bf16)b.w;
  return t.u;
}
// async global->LDS DMA, 16B/lane; LDS dest = wave-uniform base + lane*16
__device__ __forceinline__ void dma16(const void* g, void* l) {
  __builtin_amdgcn_global_load_lds(
      (const __attribute__((address_space(1))) unsigned int*)g,
      (__attribute__((address_space(3))) unsigned int*)l, 16, 0, 0);
}
// raw v_exp_f32 (D = 2^S0); s_nop covers the trans->use wait state the
// compiler can't see through the asm.
__device__ __forceinline__ float exp2_fast(float x) {
  float r;
  asm("v_exp_f32 %0, %1\n\ts_nop 1" : "=v"(r) : "v"(x));
  return r;
}
// XOR-swizzled 16B-chunk index for a 128x32 bf16 tile (4 chunks/row).
__device__ __forceinline__ int chunk_of(int row, int gc) {
  return row * 4 + (gc ^ ((row >> 1) & 3));
}

// -------- weight transpose+convert+scale: W[K][N] fp32 -> Wt[N][K] bf16 ----
__global__ __launch_bounds__(256) void transpose_k(const float* __restrict__ W,
                                                   __bf16* __restrict__ Wt, int K, int N,
                                                   float scale) {
  __shared__ __bf16 t[32][33];
  int tx = threadIdx.x & 31, ty = threadIdx.x >> 5;
  int n0 = blockIdx.x * 32, k0 = blockIdx.y * 32;
#pragma unroll
  for (int r = 0; r < 32; r += 8)
    t[ty + r][tx] = (__bf16)(W[(size_t)(k0 + ty + r) * N + n0 + tx] * scale);
  __syncthreads();
#pragma unroll
  for (int r = 0; r < 32; r += 8) Wt[(size_t)(n0 + ty + r) * K + k0 + tx] = t[tx][ty + r];
}

// -------- GEMM core: C = A[M,K] @ Bt[N,K]^T + bscale*bias --------
// 128x128 tile, BK=32, 4 waves 2x2, 4x4 16x16x32 bf16 mfma frags.
template <typename AT, typename CT>
__device__ __forceinline__ void gemm_core(__bf16* As, __bf16* Bs,
                                          const AT* __restrict__ A,
                                          const __bf16* __restrict__ Bt,
                                          const float* __restrict__ bias,
                                          CT* __restrict__ C,
                                          int M, int N, int K, int lda, int trans,
                                          int m0, int n0, float bscale) {
  const int tid = threadIdx.x;
  const int lane = tid & 63, wave = tid >> 6;
  const int g = lane >> 4, l16 = lane & 15;
  const int wr = wave >> 1, wc = wave & 1;
  int aoff[4], boff[4];
#pragma unroll
  for (int mf = 0; mf < 4; mf++) aoff[mf] = chunk_of(wr * 64 + mf * 16 + l16, g) * 8;
#pragma unroll
  for (int nf = 0; nf < 4; nf++) boff[nf] = chunk_of(wc * 64 + nf * 16 + l16, g) * 8;

  f32x4 acc[4][4] = {};
  for (int k0 = 0; k0 < K; k0 += 32) {
    __syncthreads();
    if constexpr (sizeof(AT) == 2) {       // bf16 A: DMA, 2 issues/wave
#pragma unroll
      for (int rnd = 0; rnd < 2; rnd++) {
        int cstart = wave * 128 + rnd * 64;
        int p = cstart + lane;
        int row = p >> 2, gc = (p & 3) ^ ((row >> 1) & 3);
        dma16((const __bf16*)A + (size_t)(m0 + row) * lda + k0 + gc * 8,
              As + (size_t)cstart * 8);
      }
    } else {                               // fp32 A: load+convert
#pragma unroll
      for (int i = 0; i < 2; i++) {
        int p = tid + i * 256;
        int row = p >> 2, gc = (p & 3) ^ ((row >> 1) & 3);
        const float* ap = (const float*)A + (size_t)(m0 + row) * lda + k0 + gc * 8;
        float4 f0 = *(const float4*)ap;
        float4 f1 = *(const float4*)(ap + 4);
        *(uint4*)(As + p * 8) = pack8(f0, f1);
      }
    }
#pragma unroll
    for (int rnd = 0; rnd < 2; rnd++) {    // B: always bf16 DMA
      int cstart = wave * 128 + rnd * 64;
      int p = cstart + lane;
      int row = p >> 2, gc = (p & 3) ^ ((row >> 1) & 3);
      dma16(Bt + (size_t)(n0 + row) * (size_t)K + k0 + gc * 8,
            Bs + (size_t)cstart * 8);
    }
    __syncthreads();
    bf16x8 af[4], bff[4];
#pragma unroll
    for (int mf = 0; mf < 4; mf++) af[mf]  = ld16v(As + aoff[mf]);
#pragma unroll
    for (int nf = 0; nf < 4; nf++) bff[nf] = ld16v(Bs + boff[nf]);
#pragma unroll
    for (int mf = 0; mf < 4; mf++)
#pragma unroll
      for (int nf = 0; nf < 4; nf++)
        acc[mf][nf] = __builtin_amdgcn_mfma_f32_16x16x32_bf16(af[mf], bff[nf], acc[mf][nf], 0, 0, 0);
  }
#pragma unroll
  for (int nf = 0; nf < 4; nf++) {
    int col = n0 + wc * 64 + nf * 16 + l16;
    float bv = bias[col] * bscale;
#pragma unroll
    for (int mf = 0; mf < 4; mf++) {
      int rowb = m0 + wr * 64 + mf * 16 + g * 4;
      if constexpr (sizeof(CT) == 2) {
        if (trans) {
          union { __bf16 h[4]; uint2 u; } pk;
#pragma unroll
          for (int r = 0; r < 4; r++) pk.h[r] = (__bf16)(acc[mf][nf][r] + bv);
          *(uint2*)&((__bf16*)C)[(size_t)col * M + rowb] = pk.u;   // C^T[n][m]
        } else {
#pragma unroll
          for (int r = 0; r < 4; r++)
            ((__bf16*)C)[(size_t)(rowb + r) * N + col] = (__bf16)(acc[mf][nf][r] + bv);
        }
      } else {
#pragma unroll
        for (int r = 0; r < 4; r++)
          ((float*)C)[(size_t)(rowb + r) * N + col] = acc[mf][nf][r] + bv;
      }
    }
  }
}

__global__ __launch_bounds__(256) void gemm_f_b(const float* __restrict__ A,
                                                const __bf16* __restrict__ Bt,
                                                const float* __restrict__ bias,
                                                __bf16* __restrict__ C,
                                                int M, int N, int K, int lda, int trans,
                                                float bscale) {
  __shared__ __align__(16) __bf16 As[128 * 32];
  __shared__ __align__(16) __bf16 Bs[128 * 32];
  gemm_core<float, __bf16>(As, Bs, A, Bt, bias, C, M, N, K, lda, trans,
                           blockIdx.x * 128, blockIdx.y * 128, bscale);
}

__global__ __launch_bounds__(256) void gemm_b_f(const __bf16* __restrict__ A,
                                                const __bf16* __restrict__ Bt,
                                                const float* __restrict__ bias,
                                                float* __restrict__ C,
                                                int M, int N, int K, int lda, int trans) {
  __shared__ __align__(16) __bf16 As[128 * 32];
  __shared__ __align__(16) __bf16 Bs[128 * 32];
  gemm_core<__bf16, float>(As, Bs, A, Bt, bias, C, M, N, K, lda, trans,
                           blockIdx.x * 128, blockIdx.y * 128, 1.0f);
}

__global__ __launch_bounds__(256) void gemm_kv(const float* __restrict__ A0, const __bf16* __restrict__ B0t,
                                               const float* __restrict__ b0, __bf16* __restrict__ C0,
                                               const float* __restrict__ A1, const __bf16* __restrict__ B1t,
                                               const float* __restrict__ b1, __bf16* __restrict__ C1) {
  __shared__ __align__(16) __bf16 As[128 * 32];
  __shared__ __align__(16) __bf16 Bs[128 * 32];
  if (blockIdx.z == 0)
    gemm_core<float, __bf16>(As, Bs, A0, B0t, b0, C0, 2048, 1024, 4096, 4096, 0,
                             blockIdx.x * 128, blockIdx.y * 128, 1.0f);
  else
    gemm_core<float, __bf16>(As, Bs, A1, B1t, b1, C1, 2048, 1024, 4096, 4096, 1,
                             blockIdx.x * 128, blockIdx.y * 128, 1.0f);
}

// -------- flash attention --------
// Round-5 restructure (round-4: QBLK=64, 3 syncthreads/tile incl. a
// vmcnt(0)-drain right after staging -> every tile eats the full L2 staging
// latency; MfmaUtil 16%, VALUBusy 41%, no pipe >42% => stall-bound):
//  * QBLK=128, 8 waves x 16 q-rows, grid 64x8 = 512 blocks (2/CU, 16 w/CU).
//  * Double-buffered K/V tiles + one-tile prefetch: per tile
//      lgkmcnt(0)+barrier ; issue DMA(t+1)->buf^1 ; vmcnt(4)+barrier ; compute
//    Counted vmcnt (T4): the 4 in-flight prefetch DMAs never drain in-loop,
//    staging latency hides under the whole tile's compute.
//  * P tile [128][64] XOR-chunk-swizzled, wave-private rows -> no 3rd barrier.
//  * LDS = 2*16K (K) + 2*16K (V) + 16K (P) = 80KB exactly -> 2 blocks/CU.
//  * exp2 via raw v_exp_f32 asm (libm exp2f is ~5 inst; this is the VALUBusy
//    regression from round 4).
__global__ __launch_bounds__(512, 4) void attn_k(const __bf16* __restrict__ q,
                                                 const __bf16* __restrict__ k,
                                                 const __bf16* __restrict__ vt,
                                                 __bf16* __restrict__ o) {
  __shared__ __align__(16) __bf16 ks[2][64 * 128];   // K tile [s][e], swizzled chunks
  __shared__ __align__(16) __bf16 vs[2][128 * 64];   // V^T tile [e][s], swizzled chunks
  __shared__ __align__(16) __bf16 ps[128 * 64];      // P tile [q][s], swizzled chunks
  const int tid = threadIdx.x, lane = tid & 63, wave = tid >> 6;
  const int g = lane >> 4, l16 = lane & 15;
  const int h = blockIdx.y, q0 = blockIdx.x * 128;

  const __bf16* kbase = k + (size_t)h * 128;
  const __bf16* vbase = vt + (size_t)(h * 128) * 2048;

  bf16x8 qf[4];                    // Q rows q0+wave*16+l16 (scale pre-folded)
#pragma unroll
  for (int kk = 0; kk < 4; kk++)
    qf[kk] = ld16v(q + (size_t)(q0 + wave * 16 + l16) * 1024 + h * 128 + kk * 32 + g * 8);

  f32x4 accO[8] = {};
  float m_i[4], l_i[4];
#pragma unroll
  for (int r = 0; r < 4; r++) { m_i[r] = -1e30f; l_i[r] = 0.f; }

  // prologue: stage tile 0 into buf 0 (4 DMA issues/wave)
  {
#pragma unroll
    for (int i = 0; i < 2; i++) {
      int c = wave * 128 + i * 64 + lane;
      int row = c >> 4, gc = (c & 15) ^ (row & 7);
      dma16(kbase + (size_t)row * 1024 + gc * 8, &ks[0][(wave * 128 + i * 64) * 8]);
    }
#pragma unroll
    for (int i = 0; i < 2; i++) {
      int c = wave * 128 + i * 64 + lane;
      int row = c >> 3, cc = (c & 7) ^ (row & 7);
      dma16(vbase + (size_t)row * 2048 + cc * 8, &vs[0][(wave * 128 + i * 64) * 8]);
    }
  }

  for (int t = 0; t < 32; t++) {
    const int cur = t & 1;
    // (A) all waves done reading buf^1 (prev tile's compute) -> safe to DMA
    asm volatile("s_waitcnt lgkmcnt(0)" ::: "memory");
    __builtin_amdgcn_s_barrier();
    __builtin_amdgcn_sched_barrier(0);
    {                               // prefetch tile t+1 into buf^1 (wraps at end)
      const int sn = ((t + 1) & 31) * 64;
#pragma unroll
      for (int i = 0; i < 2; i++) {
        int c = wave * 128 + i * 64 + lane;
        int row = c >> 4, gc = (c & 15) ^ (row & 7);
        dma16(kbase + (size_t)(sn + row) * 1024 + gc * 8,
              &ks[cur ^ 1][(wave * 128 + i * 64) * 8]);
      }
#pragma unroll
      for (int i = 0; i < 2; i++) {
        int c = wave * 128 + i * 64 + lane;
        int row = c >> 3, cc = (c & 7) ^ (row & 7);
        dma16(vbase + (size_t)row * 2048 + sn + cc * 8,
              &vs[cur ^ 1][(wave * 128 + i * 64) * 8]);
      }
    }
    // (B) tile t staged by ALL waves (own vmcnt(4) + barrier); prefetch stays
    // in flight across the barrier (counted vmcnt, never 0 in-loop).
    asm volatile("s_waitcnt vmcnt(4)" ::: "memory");
    __builtin_amdgcn_s_barrier();
    __builtin_amdgcn_sched_barrier(0);

    f32x4 sc[4] = {};
    __builtin_amdgcn_s_setprio(1);
#pragma unroll
    for (int kk = 0; kk < 4; kk++) {  // QK^T, contract e=128
      bf16x8 kf[4];
#pragma unroll
      for (int nf = 0; nf < 4; nf++) {
        int row = nf * 16 + l16;
        kf[nf] = ld16v(&ks[cur][(row * 16 + ((kk * 4 + g) ^ (row & 7))) * 8]);
      }
#pragma unroll
      for (int nf = 0; nf < 4; nf++)
        sc[nf] = __builtin_amdgcn_mfma_f32_16x16x32_bf16(qf[kk], kf[nf], sc[nf], 0, 0, 0);
    }
    __builtin_amdgcn_s_setprio(0);

    // online softmax, base-2 domain; row g*4+r lives in the 16 lanes of group g
#pragma unroll
    for (int r = 0; r < 4; r++) {
      float mx = fmaxf(fmaxf(sc[0][r], sc[1][r]), fmaxf(sc[2][r], sc[3][r]));
#pragma unroll
      for (int off = 1; off < 16; off <<= 1) mx = fmaxf(mx, __shfl_xor(mx, off));
      float mn = fmaxf(m_i[r], mx);
      float alpha = exp2_fast(m_i[r] - mn);
      float rs = 0.f;
#pragma unroll
      for (int nf = 0; nf < 4; nf++) {
        float p = exp2_fast(sc[nf][r] - mn);
        sc[nf][r] = p;
        rs += p;
      }
#pragma unroll
      for (int off = 1; off < 16; off <<= 1) rs += __shfl_xor(rs, off);
      m_i[r] = mn;
      l_i[r] = l_i[r] * alpha + rs;
#pragma unroll
      for (int ef = 0; ef < 8; ef++) accO[ef][r] *= alpha;
    }

    // P write: wave-private rows, swizzled chunks; same-wave DS order suffices
#pragma unroll
    for (int nf = 0; nf < 4; nf++)
#pragma unroll
      for (int r = 0; r < 4; r++) {
        int prow = wave * 16 + g * 4 + r;
        int cc = nf * 2 + (l16 >> 3);
        ps[(prow * 8 + (cc ^ (prow & 7))) * 8 + (l16 & 7)] = (__bf16)sc[nf][r];
      }

    __builtin_amdgcn_s_setprio(1);
#pragma unroll
    for (int kk = 0; kk < 2; kk++) {   // PV, contract s=64
      int prow = wave * 16 + l16;
      bf16x8 pf = ld16v(&ps[(prow * 8 + ((kk * 4 + g) ^ (prow & 7))) * 8]);
#pragma unroll
      for (int ef = 0; ef < 8; ef++) {
        int vrow = ef * 16 + l16;
        bf16x8 vf = ld16v(&vs[cur][(vrow * 8 + ((kk * 4 + g) ^ (vrow & 7))) * 8]);
        accO[ef] = __builtin_amdgcn_mfma_f32_16x16x32_bf16(pf, vf, accO[ef], 0, 0, 0);
      }
    }
    __builtin_amdgcn_s_setprio(0);
  }

  float inv[4];
#pragma unroll
  for (int r = 0; r < 4; r++) inv[r] = 1.0f / l_i[r];
#pragma unroll
  for (int ef = 0; ef < 8; ef++)
#pragma unroll
    for (int r = 0; r < 4; r++) {
      int row = q0 + wave * 16 + g * 4 + r;
      o[(size_t)row * 1024 + h * 128 + ef * 16 + l16] = (__bf16)(accO[ef][r] * inv[r]);
    }
}

extern "C" void kernel_launch(void* const* d_in, const int* in_sizes, int n_in,
                              void* d_out, int out_size, void* d_ws, size_t ws_size,
                              hipStream_t stream) {
  const float* Q   = (const float*)d_in[0];
  const float* Ksr = (const float*)d_in[1];
  const float* Vsr = (const float*)d_in[2];
  const float* Wq  = (const float*)d_in[3];
  const float* bq  = (const float*)d_in[4];
  const float* Wk  = (const float*)d_in[5];
  const float* bk  = (const float*)d_in[6];
  const float* Wv  = (const float*)d_in[7];
  const float* bv  = (const float*)d_in[8];
  const float* Wo  = (const float*)d_in[9];
  const float* bo  = (const float*)d_in[10];
  __bf16* ws = (__bf16*)d_ws;
  const size_t MB = 1024 * 1024;
  __bf16* qb  = ws;             // [8192,1024] (pre-scaled by qscale)
  __bf16* kb  = ws + 8  * MB;   // [2048,1024]
  __bf16* vtb = ws + 10 * MB;   // [1024,2048] = v^T
  __bf16* at  = ws + 12 * MB;   // [8192,1024]
  __bf16* WqT = ws + 20 * MB;   // [1024,1024]
  __bf16* WkT = ws + 21 * MB;   // [1024,4096]
  __bf16* WvT = ws + 25 * MB;   // [1024,4096]
  __bf16* WoT = ws + 29 * MB;   // [4096,1024]

  // 1/sqrt(512) * log2(e): softmax computed as 2^x in attn_k
  const float qscale = 0.044194173824159216f * 1.4426950408889634f;

  transpose_k<<<dim3(32, 32),  256, 0, stream>>>(Wq, WqT, 1024, 1024, qscale);
  transpose_k<<<dim3(32, 128), 256, 0, stream>>>(Wk, WkT, 4096, 1024, 1.0f);
  transpose_k<<<dim3(32, 128), 256, 0, stream>>>(Wv, WvT, 4096, 1024, 1.0f);
  transpose_k<<<dim3(128, 32), 256, 0, stream>>>(Wo, WoT, 1024, 4096, 1.0f);

  gemm_f_b<<<dim3(64, 8), 256, 0, stream>>>(Q, WqT, bq, qb, 8192, 1024, 1024, 1024, 0, qscale);
  gemm_kv<<<dim3(16, 8, 2), 256, 0, stream>>>(Ksr, WkT, bk, kb, Vsr, WvT, bv, vtb);
  attn_k<<<dim3(64, 8), 512, 0, stream>>>(qb, kb, vtb, at);
  gemm_b_f<<<dim3(64, 32), 256, 0, stream>>>(at, WoT, bo, (float*)d_out, 8192, 4096, 1024, 1024, 0);
}